// Round 15
// baseline (292.228 us; speedup 1.0000x reference)
//
#include <hip/hip_runtime.h>
#include <hip/hip_bf16.h>

#define NB 60000
#define NP 2000
#define NC 4000
#define EM_N 150000
#define EP_N 300000
#define EI_N 150000
#define POOL_N (EM_N + EP_N + EI_N)
#define SEG_TOT (NB + NB + NC)
#define SCAN_BLK 1024
#define NPART ((SEG_TOT + SCAN_BLK - 1) / SCAN_BLK)   // 122
#define BALL_TILES ((NB + 63) / 64)                   // 938
#define PLYR_TILES ((NP + 63) / 64)                   // 32
#define CTX_TILES ((NC + 63) / 64)                    // 63
#define GEMM_BLKS (6 * BALL_TILES + PLYR_TILES + CTX_TILES) // 5723
#define FILL_BLKS ((POOL_N + 255) / 256)              // 2344
#define CONVB ((NB * 16 + 255) / 256)                 // 3750
#define CONVC ((NC * 16 + 255) / 256)                 // 250
#define CONVP ((NP * 16 + 255) / 256)                 // 125
#define PREPALL_BLKS (FILL_BLKS + 512 + CONVB + CONVC + CONVP) // 6981
#define BBALL ((NB + 3) / 4)                          // 15000

// q is pre-scaled by (1/sqrt(32)) * log2(e) so TR logits feed exp2f directly.
#define QSCALE (0.17677669529663687f * 1.4426950408889634f)
#define LOG2E 1.4426950408889634f

typedef __hip_bfloat16 bf16;
typedef unsigned int u32;
typedef __attribute__((ext_vector_type(8))) short s8v;
typedef __attribute__((ext_vector_type(4))) float f4v;

__device__ __forceinline__ short f2bs(float f) {
    bf16 h = __float2bfloat16(f);
    return __builtin_bit_cast(short, h);
}
__device__ __forceinline__ float bsToF(short s) {
    return __builtin_bit_cast(float, ((unsigned)(unsigned short)s) << 16);
}
__device__ __forceinline__ float loF(u32 v) { return bsToF((short)(v & 0xffff)); }
__device__ __forceinline__ float hiF(u32 v) { return bsToF((short)(v >> 16)); }
__device__ __forceinline__ u32 packbf(float a, float b) {
    return (u32)(unsigned short)f2bs(a) | ((u32)(unsigned short)f2bs(b) << 16);
}
__device__ __forceinline__ void gl_lds16(const void* g, void* l) {
    __builtin_amdgcn_global_load_lds((const __attribute__((address_space(1))) void*)g,
                                     (__attribute__((address_space(3))) void*)l, 16, 0, 0);
}

// ---------------- merged prep: hist(+ranks) | Wt transpose | bf16 converts | player copy ----------
// Wt layout per weight (16384 ushorts): chunk-major [c0=k>>3][sc][k&7]
//   slot = (k>>3)*1024 + sc*8 + (k&7), sc = (n>>5)*32 + (n&1)*16 + ((n&31)>>1)
// xb* layout: row-major packed bf16, u32 c = cols (2c, 2c+1); row stride 64 u32.
__global__ void prep_all_kernel(const int* __restrict__ em, const int* __restrict__ ep,
                                const int* __restrict__ ei, int* __restrict__ counts,
                                int* __restrict__ ranks,
                                const float* __restrict__ W0, const float* __restrict__ W1,
                                const float* __restrict__ W2, const float* __restrict__ W3,
                                const float* __restrict__ W4, const float* __restrict__ W5,
                                const float* __restrict__ W6, const float* __restrict__ W7,
                                ushort* __restrict__ Wt,
                                const float* __restrict__ x_ball, const float* __restrict__ x_context,
                                const float* __restrict__ x_player,
                                u32* __restrict__ xbB, u32* __restrict__ xbC, u32* __restrict__ xbP,
                                float* __restrict__ out) {
    if (blockIdx.x < FILL_BLKS) {
        int t = blockIdx.x * 256 + threadIdx.x;
        if (t < EM_N) ranks[t] = atomicAdd(&counts[em[EM_N + t]], 1);
        else if (t < EM_N + EP_N) ranks[t] = atomicAdd(&counts[NB + ep[EP_N + (t - EM_N)]], 1);
        else if (t < POOL_N) ranks[t] = atomicAdd(&counts[2 * NB + ei[EI_N + (t - EM_N - EP_N)]], 1);
        return;
    }
    int b2 = blockIdx.x - FILL_BLKS;
    if (b2 < 512) {
        // ---- Wt transpose ----
        int t = b2 * 256 + threadIdx.x;
        int w = t >> 14, r = t & 16383, k = r >> 7, n = r & 127;
        const float* W = (w == 0) ? W0 : (w == 1) ? W1 : (w == 2) ? W2 : (w == 3) ? W3
                       : (w == 4) ? W4 : (w == 5) ? W5 : (w == 6) ? W6 : W7;
        int sc = (n >> 5) * 32 + ((n & 1) << 4) + ((n & 31) >> 1);
        Wt[w * 16384 + (k >> 3) * 1024 + sc * 8 + (k & 7)] = (unsigned short)f2bs(W[k * 128 + n]);
        return;
    }
    int b3 = b2 - 512;
    if (b3 < CONVB) {                    // ball fp32 -> bf16 (8 floats / thread)
        int idx = b3 * 256 + threadIdx.x;
        const float4* p = (const float4*)(x_ball + (size_t)idx * 8);
        float4 u = p[0], v = p[1];
        ((uint4*)xbB)[idx] = make_uint4(packbf(u.x, u.y), packbf(u.z, u.w),
                                        packbf(v.x, v.y), packbf(v.z, v.w));
    } else if (b3 < CONVB + CONVC) {     // ctx
        int idx = (b3 - CONVB) * 256 + threadIdx.x;
        const float4* p = (const float4*)(x_context + (size_t)idx * 8);
        float4 u = p[0], v = p[1];
        ((uint4*)xbC)[idx] = make_uint4(packbf(u.x, u.y), packbf(u.z, u.w),
                                        packbf(v.x, v.y), packbf(v.z, v.w));
    } else {                             // player: bf16 + fp32 passthrough to out
        int idx = (b3 - CONVB - CONVC) * 256 + threadIdx.x;
        const float4* p = (const float4*)(x_player + (size_t)idx * 8);
        float4 u = p[0], v = p[1];
        ((uint4*)xbP)[idx] = make_uint4(packbf(u.x, u.y), packbf(u.z, u.w),
                                        packbf(v.x, v.y), packbf(v.z, v.w));
        float4* po = (float4*)(out + (size_t)(NB + NC) * 128 + (size_t)idx * 8);
        po[0] = u; po[1] = v;
    }
}

// ---------------- fused scan: block-local scan + atomic base ----------------
__global__ void scan_kernel(const int* __restrict__ counts, int* __restrict__ offsets,
                            int* __restrict__ gbase) {
    __shared__ int sd[256];
    __shared__ int sbase;
    int b = blockIdx.x, tid = threadIdx.x;
    int base = b * SCAN_BLK + tid * 4;
    int v[4]; int ts = 0;
#pragma unroll
    for (int j = 0; j < 4; j++) { int idx = base + j; v[j] = (idx < SEG_TOT) ? counts[idx] : 0; ts += v[j]; }
    sd[tid] = ts;
    for (int off = 1; off < 256; off <<= 1) {
        __syncthreads(); int t = (tid >= off) ? sd[tid - off] : 0;
        __syncthreads(); sd[tid] += t;
    }
    __syncthreads();
    if (tid == 255) sbase = atomicAdd(gbase, sd[255]);
    __syncthreads();
    int run = sd[tid] - ts + sbase;
#pragma unroll
    for (int j = 0; j < 4; j++) {
        int idx = base + j;
        if (idx < SEG_TOT) offsets[idx] = run;
        run += v[j];
    }
}

// ---------------- merged: one-weight one-tile GEMM blocks + atomic-free pool-fill (fill LAST) ----
// kvP layout: [row][ k(64 u32) | v(64 u32) ] -> full-line writes from both k and v jobs.
__global__ __launch_bounds__(256) void gemm6_fill_kernel(
    const u32* __restrict__ xbB, const u32* __restrict__ xbP, const u32* __restrict__ xbC,
    const float* __restrict__ Aball, const float* __restrict__ Actx,
    const ushort* __restrict__ Wt,
    const float* __restrict__ bq, const float* __restrict__ bk,
    const float* __restrict__ bv_, const float* __restrict__ bskip, const float* __restrict__ bl,
    u32* __restrict__ xrP, u32* __restrict__ qP, u32* __restrict__ kvP,
    u32* __restrict__ skipP, u32* __restrict__ xlP, u32* __restrict__ xwP,
    u32* __restrict__ ctxlinP,
    const int* __restrict__ em, const int* __restrict__ ep, const int* __restrict__ ei,
    const float* __restrict__ ea_p, const int* __restrict__ offsets,
    const int* __restrict__ ranks, int2* __restrict__ pool) {
    __shared__ ushort lds[16384];   // 32KB: one 128x128 bf16 weight
    if (blockIdx.x >= GEMM_BLKS) {
        int t = (blockIdx.x - GEMM_BLKS) * 256 + threadIdx.x;
        int seg, s; float ea = 0.f;
        if (t < EM_N) { s = em[t]; seg = em[EM_N + t]; }
        else if (t < EM_N + EP_N) { int e = t - EM_N; s = ep[e]; seg = NB + ep[EP_N + e]; ea = ea_p[e]; }
        else if (t < POOL_N) { int e = t - EM_N - EP_N; s = ei[e]; seg = 2 * NB + ei[EI_N + e]; }
        else return;
        int pos = offsets[seg] + ranks[t];   // no atomics
        pool[pos] = make_int2(s, __float_as_int(ea));
        return;
    }
    const int tid = threadIdx.x;
    const int lane = tid & 63;
    const int wv = tid >> 6;
    const int quad = lane >> 4, l16 = lane & 15;

    // ---- job decode (block-uniform): one weight x one 64-row tile ----
    int bid = blockIdx.x;
    int w, tile, M;
    const u32* A;
    if (bid < 6 * BALL_TILES) {
        int widx = bid / BALL_TILES;         // 0..5
        w = (widx < 5) ? widx : 6;           // weights 0..4 and 6 operate on ball rows
        tile = bid - widx * BALL_TILES; M = NB; A = xbB;
    } else if (bid < 6 * BALL_TILES + PLYR_TILES) {
        w = 5; tile = bid - 6 * BALL_TILES; M = NP; A = xbP;
    } else {
        w = 7; tile = bid - 6 * BALL_TILES - PLYR_TILES; M = NC; A = xbC;
    }
    u32* op; const float* bp = nullptr; const float* resid = nullptr; float scale = 1.f;
    int ostride = 64, ooff = 0;
    switch (w) {
        case 0: op = xrP; break;
        case 1: op = qP; bp = bq; scale = QSCALE; break;
        case 2: op = kvP; bp = bk; ostride = 128; ooff = 0; break;
        case 3: op = kvP; bp = bv_; ostride = 128; ooff = 64; break;
        case 4: op = skipP; bp = bskip; resid = Aball; break;
        case 5: op = xlP; break;
        case 6: op = xwP; break;
        default: op = ctxlinP; bp = bl; resid = Actx; break;
    }

    // ---- stage weight (linear copy; layout makes ds reads conflict-free) ----
    {
        const ushort* src = Wt + w * 16384;
#pragma unroll
        for (int p = 0; p < 8; p++)
            gl_lds16(src + (size_t)(p * 256 + tid) * 8, lds + p * 2048 + wv * 512);
    }

    // A fragments (issued while the stage flies)
    s8v a[4];
    {
        int r0 = tile * 64 + wv * 16 + l16; if (r0 >= M) r0 = M - 1;
        const s8v* ap = (const s8v*)(A + (size_t)r0 * 64 + quad * 4);
#pragma unroll
        for (int kt = 0; kt < 4; kt++) a[kt] = ap[kt * 4];
    }
    // bias preload (depends only on t,l16)
    float2 bias2[4];
#pragma unroll
    for (int t = 0; t < 4; t++)
        bias2[t] = bp ? ((const float2*)bp)[t * 16 + l16] : make_float2(0.f, 0.f);
    __syncthreads();   // weight staged

    const int mbase = tile * 64 + wv * 16;
#pragma unroll
    for (int t = 0; t < 4; t++) {
        f4v alo = {0.f, 0.f, 0.f, 0.f}, ahi = {0.f, 0.f, 0.f, 0.f};
#pragma unroll
        for (int kt = 0; kt < 4; kt++) {
            s8v blo = *(const s8v*)(lds + (kt * 4 + quad) * 1024 + (t * 32 + l16) * 8);
            s8v bhi = *(const s8v*)(lds + (kt * 4 + quad) * 1024 + (t * 32 + 16 + l16) * 8);
            alo = __builtin_amdgcn_mfma_f32_16x16x32_bf16(a[kt], blo, alo, 0, 0, 0);
            ahi = __builtin_amdgcn_mfma_f32_16x16x32_bf16(a[kt], bhi, ahi, 0, 0, 0);
        }
#pragma unroll
        for (int r = 0; r < 4; r++) {
            int row = mbase + quad * 4 + r;
            if (row < M) {
                float vlo = (alo[r] + bias2[t].x) * scale;
                float vhi = (ahi[r] + bias2[t].y) * scale;
                if (resid) {
                    float2 x2 = ((const float2*)resid)[(size_t)row * 64 + t * 16 + l16];
                    vlo += x2.x; vhi += x2.y;
                }
                op[(size_t)row * ostride + ooff + t * 16 + l16] = packbf(vlo, vhi);
            }
        }
    }
}

// ---------------- edge-batch helpers (ball path) ----------------
__device__ __forceinline__ void gat_batch(const u32 xv[4], const bool ok[4],
                                          float xr0, float xr1, float attx, float atty,
                                          float& n0, float& n1, float& deg) {
    float p[4], xa[4], xb[4];
#pragma unroll
    for (int i = 0; i < 4; i++) {
        xa[i] = loF(xv[i]); xb[i] = hiF(xv[i]);
        float u0 = xa[i] + xr0; u0 = u0 > 0.f ? u0 : 0.2f * u0;
        float u1 = xb[i] + xr1; u1 = u1 > 0.f ? u1 : 0.2f * u1;
        p[i] = u0 * attx + u1 * atty;
    }
#pragma unroll
    for (int m = 1; m <= 8; m <<= 1) {
#pragma unroll
        for (int i = 0; i < 4; i++) p[i] += __shfl_xor(p[i], m);
    }
#pragma unroll
    for (int i = 0; i < 4; i++) {
        p[i] = ok[i] ? exp2f(p[i]) : 0.f;
        n0 += p[i] * xa[i]; n1 += p[i] * xb[i]; deg += p[i];
    }
}

__device__ __forceinline__ void tr_batch(const u32 kk[4], const u32 vv[4],
                                         const float ea[4], const bool ok[4],
                                         float q0, float q1, float dw,
                                         float& sv0, float& sv1, float& spe, float& det) {
    float p[4];
#pragma unroll
    for (int i = 0; i < 4; i++) p[i] = q0 * loF(kk[i]) + q1 * hiF(kk[i]);
#pragma unroll
    for (int m = 1; m <= 8; m <<= 1) {
#pragma unroll
        for (int i = 0; i < 4; i++) p[i] += __shfl_xor(p[i], m);
    }
#pragma unroll
    for (int i = 0; i < 4; i++) {
        p[i] = ok[i] ? exp2f(p[i] + ea[i] * dw) : 0.f;
        sv0 += p[i] * loF(vv[i]); sv1 += p[i] * hiF(vv[i]);
        spe += p[i] * ea[i]; det += p[i];
    }
}

// ---------------- merged: ctx blocks FIRST (longest, ~37.5-edge serial gather-mean)
// then ball blocks -> long ctx chains overlap the bulk ball phase instead of forming the tail.
// LayerNorm uses fused sum/sumsq single-pass reduction (var = E[x^2]-mu^2).
// Ball path wraps its VALU-dense edge-compute in s_setprio(1) (T5: independent-wave case).
__global__ __launch_bounds__(256) void ball_sage_kernel(
    const u32* __restrict__ xlP, const u32* __restrict__ xrP, const u32* __restrict__ qP,
    const u32* __restrict__ kvP, const u32* __restrict__ skipP, const u32* __restrict__ xwP,
    const u32* __restrict__ ctxlinP,
    const float* __restrict__ g_att, const float* __restrict__ g_b, const float* __restrict__ We,
    const int* __restrict__ offsets, const int* __restrict__ counts,
    const int2* __restrict__ pool,
    const float* __restrict__ ln_g, const float* __restrict__ ln_b,
    const float* __restrict__ cg, const float* __restrict__ cb,
    float* __restrict__ out) {
    __shared__ float part[4][128];
    const int wv = threadIdx.x >> 6, l = threadIdx.x & 63;

    if (blockIdx.x < NC) {
        // ---- ctx: gather-mean xw + ctxlin + LN (2-deep pipelined gather) ----
        int c = blockIdx.x;
        int beg = offsets[2 * NB + c], cnt = counts[2 * NB + c];
        float s0 = 0.f, s1 = 0.f;
        int j = wv;
        if (j < cnt) {
            int i0 = pool[beg + j].x;
            int idx1 = (j + 4 < cnt) ? beg + j + 4 : 0;
            int i1 = pool[idx1].x;
            u32 x0 = xwP[(size_t)i0 * 64 + l];
            u32 x1 = xwP[(size_t)i1 * 64 + l];
            for (; j < cnt; j += 4) {
                int idx2 = (j + 8 < cnt) ? beg + j + 8 : 0;
                int i2 = pool[idx2].x;
                s0 += loF(x0); s1 += hiF(x0);
                x0 = x1;
                x1 = xwP[(size_t)i2 * 64 + l];
            }
        }
        part[wv][l * 2] = s0; part[wv][l * 2 + 1] = s1;
        __syncthreads();
        if (wv == 0) {
            float m = fmaxf((float)cnt, 1.f);
            u32 cl = ctxlinP[(size_t)c * 64 + l];
            float v0 = (part[0][l * 2] + part[1][l * 2] + part[2][l * 2] + part[3][l * 2]) / m + loF(cl);
            float v1 = (part[0][l * 2 + 1] + part[1][l * 2 + 1] + part[2][l * 2 + 1] + part[3][l * 2 + 1]) / m + hiF(cl);
            float s = v0 + v1;
            float s2 = v0 * v0 + v1 * v1;
#pragma unroll
            for (int m2 = 1; m2 <= 32; m2 <<= 1) {
                s += __shfl_xor(s, m2);
                s2 += __shfl_xor(s2, m2);
            }
            float mu = s * (1.f / 128.f);
            float var = s2 * (1.f / 128.f) - mu * mu;
            float inv = rsqrtf(var + 1e-5f);
            float d0 = v0 - mu, d1 = v1 - mu;
            float2 g2 = ((const float2*)cg)[l];
            float2 b2 = ((const float2*)cb)[l];
            ((float2*)out)[(size_t)(NB + c) * 64 + l] =
                make_float2(d0 * inv * g2.x + b2.x, d1 * inv * g2.y + b2.y);
        }
        return;
    }

    // ---- ball path: one wave per node, pairing (2l,2l+1), head = l>>4 ----
    const int d = (blockIdx.x - NC) * 4 + wv;
    const size_t rowD = (size_t)d * 64;
    const int ds = __builtin_amdgcn_readfirstlane(d);

    // early issue: per-node rows
    u32 xr2 = xrP[rowD + l];
    u32 q2 = qP[rowD + l];
    u32 sk = skipP[rowD + l];

    // scalar segment metadata + scalar pool prefetch (both relations in parallel)
    const int begG = offsets[ds], cntG = counts[ds];
    const int begT = offsets[NB + ds], cntT = counts[NB + ds];
    int gS[8];
#pragma unroll
    for (int i = 0; i < 8; i++) { int idx = (i < cntG) ? begG + i : 0; gS[i] = pool[idx].x; }
    int tS[8]; float tE[8];
#pragma unroll
    for (int i = 0; i < 8; i++) {
        int idx = (i < cntT) ? begT + i : 0;
        int2 pr = pool[idx]; tS[i] = pr.x; tE[i] = __int_as_float(pr.y);
    }

    // issue all gathers for the <=8 fast path (both relations in flight together)
    u32 gx[8];
    if (cntG > 0) {
#pragma unroll
        for (int i = 0; i < 4; i++) gx[i] = xlP[(size_t)gS[i] * 64 + l];
        if (cntG > 4) {
#pragma unroll
            for (int i = 4; i < 8; i++) gx[i] = xlP[(size_t)gS[i] * 64 + l];
        }
    }
    u32 kk[8], vv[8];
    if (cntT > 0) {
#pragma unroll
        for (int i = 0; i < 4; i++) {
            kk[i] = kvP[(size_t)tS[i] * 128 + l];
            vv[i] = kvP[(size_t)tS[i] * 128 + 64 + l];
        }
        if (cntT > 4) {
#pragma unroll
            for (int i = 4; i < 8; i++) {
                kk[i] = kvP[(size_t)tS[i] * 128 + l];
                vv[i] = kvP[(size_t)tS[i] * 128 + 64 + l];
            }
        }
    }

    // gathers issued; prioritize this wave's compute phase (T5: independent waves)
    __builtin_amdgcn_s_setprio(1);

    // TR edge-weight projection (q is pre-scaled by QSCALE)
    float q0 = loF(q2), q1 = hiF(q2);
    float2 we = ((const float2*)We)[l];
    float dw = q0 * we.x + q1 * we.y;
#pragma unroll
    for (int m = 1; m <= 8; m <<= 1) dw += __shfl_xor(dw, m);

    // ======== GATv2 (att pre-scaled by log2e for exp2f) ========
    float2 attv = ((const float2*)g_att)[l];
    float attx = attv.x * LOG2E, atty = attv.y * LOG2E;
    float xr0 = loF(xr2), xr1 = hiF(xr2);
    float n0 = 0.f, n1 = 0.f, deg = 0.f;
    if (cntG > 0) {
        bool ok[4];
#pragma unroll
        for (int i = 0; i < 4; i++) ok[i] = (i < cntG);
        gat_batch(&gx[0], ok, xr0, xr1, attx, atty, n0, n1, deg);
        if (cntG > 4) {
            bool ok2[4];
#pragma unroll
            for (int i = 0; i < 4; i++) ok2[i] = (4 + i < cntG);
            gat_batch(&gx[4], ok2, xr0, xr1, attx, atty, n0, n1, deg);
        }
        for (int j = 8; j < cntG; j += 4) {     // rare tail
            bool ok3[4]; u32 xv[4];
#pragma unroll
            for (int i = 0; i < 4; i++) {
                ok3[i] = (j + i < cntG);
                int idx = ok3[i] ? begG + j + i : 0;
                xv[i] = xlP[(size_t)pool[idx].x * 64 + l];
            }
            gat_batch(xv, ok3, xr0, xr1, attx, atty, n0, n1, deg);
        }
    }
    float gat0 = n0 / (deg + 1e-16f), gat1 = n1 / (deg + 1e-16f);

    // ======== TransformerConv ========
    float sv0 = 0.f, sv1 = 0.f, spe = 0.f, det = 0.f;
    if (cntT > 0) {
        bool ok[4];
#pragma unroll
        for (int i = 0; i < 4; i++) ok[i] = (i < cntT);
        tr_batch(&kk[0], &vv[0], &tE[0], ok, q0, q1, dw, sv0, sv1, spe, det);
        if (cntT > 4) {
            bool ok2[4];
#pragma unroll
            for (int i = 0; i < 4; i++) ok2[i] = (4 + i < cntT);
            tr_batch(&kk[4], &vv[4], &tE[4], ok2, q0, q1, dw, sv0, sv1, spe, det);
        }
        for (int j = 8; j < cntT; j += 4) {     // rare tail
            bool ok3[4]; u32 kt2[4], vt2[4]; float ea[4];
#pragma unroll
            for (int i = 0; i < 4; i++) {
                ok3[i] = (j + i < cntT);
                int idx = ok3[i] ? begT + j + i : 0;
                int2 pr = pool[idx];
                ea[i] = __int_as_float(pr.y);
                kt2[i] = kvP[(size_t)pr.x * 128 + l];
                vt2[i] = kvP[(size_t)pr.x * 128 + 64 + l];
            }
            tr_batch(kt2, vt2, ea, ok3, q0, q1, dw, sv0, sv1, spe, det);
        }
    }
    float tr0 = (sv0 + spe * we.x) / (det + 1e-16f);
    float tr1 = (sv1 + spe * we.y) / (det + 1e-16f);

    __builtin_amdgcn_s_setprio(0);

    // ======== residual(skipP has x_ball+bskip; add g_b here) + LayerNorm (fused sum/sumsq) ========
    float2 gb2 = ((const float2*)g_b)[l];
    float val0 = loF(sk) + gb2.x + gat0 + tr0;
    float val1 = hiF(sk) + gb2.y + gat1 + tr1;
    float s = val0 + val1;
    float s2 = val0 * val0 + val1 * val1;
#pragma unroll
    for (int m = 1; m <= 32; m <<= 1) {
        s += __shfl_xor(s, m);
        s2 += __shfl_xor(s2, m);
    }
    float mu = s * (1.f / 128.f);
    float var = s2 * (1.f / 128.f) - mu * mu;
    float inv = rsqrtf(var + 1e-5f);
    float d0 = val0 - mu, d1 = val1 - mu;
    float2 g2 = ((const float2*)ln_g)[l];
    float2 b2 = ((const float2*)ln_b)[l];
    ((float2*)out)[rowD + l] = make_float2(d0 * inv * g2.x + b2.x, d1 * inv * g2.y + b2.y);
}

extern "C" void kernel_launch(void* const* d_in, const int* in_sizes, int n_in,
                              void* d_out, int out_size, void* d_ws, size_t ws_size,
                              hipStream_t stream) {
    const float* x_ball = (const float*)d_in[0];
    const float* x_player = (const float*)d_in[1];
    const float* x_context = (const float*)d_in[2];
    const int* em = (const int*)d_in[3];
    const int* ep = (const int*)d_in[4];
    const int* ei = (const int*)d_in[5];
    const float* ea_p = (const float*)d_in[6];
    const float* g_Wl = (const float*)d_in[7];
    const float* g_Wr = (const float*)d_in[8];
    const float* g_att = (const float*)d_in[9];
    const float* g_b = (const float*)d_in[10];
    const float* t_Wq = (const float*)d_in[11];
    const float* t_bq = (const float*)d_in[12];
    const float* t_Wk = (const float*)d_in[13];
    const float* t_bk = (const float*)d_in[14];
    const float* t_Wv = (const float*)d_in[15];
    const float* t_bv = (const float*)d_in[16];
    const float* t_We = (const float*)d_in[17];
    const float* t_Wskip = (const float*)d_in[18];
    const float* t_bskip = (const float*)d_in[19];
    const float* s_Wl = (const float*)d_in[20];
    const float* s_bl = (const float*)d_in[21];
    const float* s_Wr = (const float*)d_in[22];
    const float* ln_ball_g = (const float*)d_in[23];
    const float* ln_ball_b = (const float*)d_in[24];
    const float* ln_ctx_g = (const float*)d_in[25];
    const float* ln_ctx_b = (const float*)d_in[26];
    float* out = (float*)d_out;

    // ---- workspace ----
    float* ws = (float*)d_ws;
    size_t o = 0;
    int* counts = (int*)(ws + o);   o += SEG_TOT;
    int* gbase = (int*)(ws + o);    o += 1;     // zeroed with counts
    int* offsets = (int*)(ws + o);  o += SEG_TOT;
    int* ranks = (int*)(ws + o);    o += POOL_N;
    if (o & 1) o++;
    int2* pool = (int2*)(ws + o);   o += (size_t)POOL_N * 2;
    o = (o + 3) & ~(size_t)3;       // 16B-align
    ushort* Wt = (ushort*)(ws + o); o += (8 * 16384) / 2;
    u32* xbB = (u32*)(ws + o);      o += (size_t)NB * 64;
    u32* xbC = (u32*)(ws + o);      o += (size_t)NC * 64;
    u32* xbP = (u32*)(ws + o);      o += (size_t)NP * 64;
    u32* xlP = (u32*)(ws + o);      o += (size_t)NP * 64;
    u32* xrP = (u32*)(ws + o);      o += (size_t)NB * 64;
    u32* qP = (u32*)(ws + o);       o += (size_t)NB * 64;
    u32* skipP = (u32*)(ws + o);    o += (size_t)NB * 64;
    u32* xwP = (u32*)(ws + o);      o += (size_t)NB * 64;
    u32* ctxlinP = (u32*)(ws + o);  o += (size_t)NC * 64;
    if (o & 1) o++;
    u32* kvP = (u32*)(ws + o);      o += (size_t)NB * 128;

    dim3 blk(256);
    hipMemsetAsync(counts, 0, (SEG_TOT + 1) * sizeof(int), stream);
    prep_all_kernel<<<PREPALL_BLKS, blk, 0, stream>>>(
        em, ep, ei, counts, ranks, g_Wr, t_Wq, t_Wk, t_Wv, t_Wskip, g_Wl, s_Wl, s_Wr, Wt,
        x_ball, x_context, x_player, xbB, xbC, xbP, out);
    scan_kernel<<<NPART, blk, 0, stream>>>(counts, offsets, gbase);
    gemm6_fill_kernel<<<GEMM_BLKS + FILL_BLKS, blk, 0, stream>>>(
        xbB, xbP, xbC, x_ball, x_context, Wt, t_bq, t_bk, t_bv, t_bskip, s_bl,
        xrP, qP, kvP, skipP, xlP, xwP, ctxlinP, em, ep, ei, ea_p, offsets, ranks, pool);
    ball_sage_kernel<<<BBALL + NC, blk, 0, stream>>>(
        xlP, xrP, qP, kvP, skipP, xwP, ctxlinP, g_att, g_b, t_We,
        offsets, counts, pool, ln_ball_g, ln_ball_b, ln_ctx_g, ln_ctx_b, out);
}

// Round 16
// 278.882 us; speedup vs baseline: 1.0479x; 1.0479x over previous
//
#include <hip/hip_runtime.h>
#include <hip/hip_bf16.h>

#define NB 60000
#define NP 2000
#define NC 4000
#define EM_N 150000
#define EP_N 300000
#define EI_N 150000
#define POOL_N (EM_N + EP_N + EI_N)
#define SEG_TOT (NB + NB + NC)
#define SCAN_BLK 1024
#define NPART ((SEG_TOT + SCAN_BLK - 1) / SCAN_BLK)   // 122
#define BALL_TILES ((NB + 63) / 64)                   // 938
#define PLYR_TILES ((NP + 63) / 64)                   // 32
#define CTX_TILES ((NC + 63) / 64)                    // 63
#define GEMM_BLKS (6 * BALL_TILES + PLYR_TILES + CTX_TILES) // 5723
#define FILL_BLKS ((POOL_N + 255) / 256)              // 2344
#define CONVB ((NB * 16 + 255) / 256)                 // 3750
#define CONVC ((NC * 16 + 255) / 256)                 // 250
#define CONVP ((NP * 16 + 255) / 256)                 // 125
#define PREPALL_BLKS (FILL_BLKS + 512 + CONVB + CONVC + CONVP) // 6981
#define BBALL ((NB + 3) / 4)                          // 15000

// q is pre-scaled by (1/sqrt(32)) * log2(e) so TR logits feed exp2f directly.
#define QSCALE (0.17677669529663687f * 1.4426950408889634f)
#define LOG2E 1.4426950408889634f

typedef __hip_bfloat16 bf16;
typedef unsigned int u32;
typedef __attribute__((ext_vector_type(8))) short s8v;
typedef __attribute__((ext_vector_type(4))) float f4v;

__device__ __forceinline__ short f2bs(float f) {
    bf16 h = __float2bfloat16(f);
    return __builtin_bit_cast(short, h);
}
__device__ __forceinline__ float bsToF(short s) {
    return __builtin_bit_cast(float, ((unsigned)(unsigned short)s) << 16);
}
__device__ __forceinline__ float loF(u32 v) { return bsToF((short)(v & 0xffff)); }
__device__ __forceinline__ float hiF(u32 v) { return bsToF((short)(v >> 16)); }
__device__ __forceinline__ u32 packbf(float a, float b) {
    return (u32)(unsigned short)f2bs(a) | ((u32)(unsigned short)f2bs(b) << 16);
}
__device__ __forceinline__ void gl_lds16(const void* g, void* l) {
    __builtin_amdgcn_global_load_lds((const __attribute__((address_space(1))) void*)g,
                                     (__attribute__((address_space(3))) void*)l, 16, 0, 0);
}

// ---------------- merged prep: hist(+ranks) | Wt transpose | bf16 converts | player copy ----------
// Wt layout per weight (16384 ushorts): chunk-major [c0=k>>3][sc][k&7]
//   slot = (k>>3)*1024 + sc*8 + (k&7), sc = (n>>5)*32 + (n&1)*16 + ((n&31)>>1)
// xb* layout: row-major packed bf16, u32 c = cols (2c, 2c+1); row stride 64 u32.
__global__ void prep_all_kernel(const int* __restrict__ em, const int* __restrict__ ep,
                                const int* __restrict__ ei, int* __restrict__ counts,
                                int* __restrict__ ranks,
                                const float* __restrict__ W0, const float* __restrict__ W1,
                                const float* __restrict__ W2, const float* __restrict__ W3,
                                const float* __restrict__ W4, const float* __restrict__ W5,
                                const float* __restrict__ W6, const float* __restrict__ W7,
                                ushort* __restrict__ Wt,
                                const float* __restrict__ x_ball, const float* __restrict__ x_context,
                                const float* __restrict__ x_player,
                                u32* __restrict__ xbB, u32* __restrict__ xbC, u32* __restrict__ xbP,
                                float* __restrict__ out) {
    if (blockIdx.x < FILL_BLKS) {
        int t = blockIdx.x * 256 + threadIdx.x;
        if (t < EM_N) ranks[t] = atomicAdd(&counts[em[EM_N + t]], 1);
        else if (t < EM_N + EP_N) ranks[t] = atomicAdd(&counts[NB + ep[EP_N + (t - EM_N)]], 1);
        else if (t < POOL_N) ranks[t] = atomicAdd(&counts[2 * NB + ei[EI_N + (t - EM_N - EP_N)]], 1);
        return;
    }
    int b2 = blockIdx.x - FILL_BLKS;
    if (b2 < 512) {
        // ---- Wt transpose ----
        int t = b2 * 256 + threadIdx.x;
        int w = t >> 14, r = t & 16383, k = r >> 7, n = r & 127;
        const float* W = (w == 0) ? W0 : (w == 1) ? W1 : (w == 2) ? W2 : (w == 3) ? W3
                       : (w == 4) ? W4 : (w == 5) ? W5 : (w == 6) ? W6 : W7;
        int sc = (n >> 5) * 32 + ((n & 1) << 4) + ((n & 31) >> 1);
        Wt[w * 16384 + (k >> 3) * 1024 + sc * 8 + (k & 7)] = (unsigned short)f2bs(W[k * 128 + n]);
        return;
    }
    int b3 = b2 - 512;
    if (b3 < CONVB) {                    // ball fp32 -> bf16 (8 floats / thread)
        int idx = b3 * 256 + threadIdx.x;
        const float4* p = (const float4*)(x_ball + (size_t)idx * 8);
        float4 u = p[0], v = p[1];
        ((uint4*)xbB)[idx] = make_uint4(packbf(u.x, u.y), packbf(u.z, u.w),
                                        packbf(v.x, v.y), packbf(v.z, v.w));
    } else if (b3 < CONVB + CONVC) {     // ctx
        int idx = (b3 - CONVB) * 256 + threadIdx.x;
        const float4* p = (const float4*)(x_context + (size_t)idx * 8);
        float4 u = p[0], v = p[1];
        ((uint4*)xbC)[idx] = make_uint4(packbf(u.x, u.y), packbf(u.z, u.w),
                                        packbf(v.x, v.y), packbf(v.z, v.w));
    } else {                             // player: bf16 + fp32 passthrough to out
        int idx = (b3 - CONVB - CONVC) * 256 + threadIdx.x;
        const float4* p = (const float4*)(x_player + (size_t)idx * 8);
        float4 u = p[0], v = p[1];
        ((uint4*)xbP)[idx] = make_uint4(packbf(u.x, u.y), packbf(u.z, u.w),
                                        packbf(v.x, v.y), packbf(v.z, v.w));
        float4* po = (float4*)(out + (size_t)(NB + NC) * 128 + (size_t)idx * 8);
        po[0] = u; po[1] = v;
    }
}

// ---------------- fused scan: block-local scan + atomic base ----------------
__global__ void scan_kernel(const int* __restrict__ counts, int* __restrict__ offsets,
                            int* __restrict__ gbase) {
    __shared__ int sd[256];
    __shared__ int sbase;
    int b = blockIdx.x, tid = threadIdx.x;
    int base = b * SCAN_BLK + tid * 4;
    int v[4]; int ts = 0;
#pragma unroll
    for (int j = 0; j < 4; j++) { int idx = base + j; v[j] = (idx < SEG_TOT) ? counts[idx] : 0; ts += v[j]; }
    sd[tid] = ts;
    for (int off = 1; off < 256; off <<= 1) {
        __syncthreads(); int t = (tid >= off) ? sd[tid - off] : 0;
        __syncthreads(); sd[tid] += t;
    }
    __syncthreads();
    if (tid == 255) sbase = atomicAdd(gbase, sd[255]);
    __syncthreads();
    int run = sd[tid] - ts + sbase;
#pragma unroll
    for (int j = 0; j < 4; j++) {
        int idx = base + j;
        if (idx < SEG_TOT) offsets[idx] = run;
        run += v[j];
    }
}

// ---------------- merged: one-weight one-tile GEMM blocks + atomic-free pool-fill (fill LAST) ----
// kvP layout: [row][ k(64 u32) | v(64 u32) ] -> full-line writes from both k and v jobs.
__global__ __launch_bounds__(256) void gemm6_fill_kernel(
    const u32* __restrict__ xbB, const u32* __restrict__ xbP, const u32* __restrict__ xbC,
    const float* __restrict__ Aball, const float* __restrict__ Actx,
    const ushort* __restrict__ Wt,
    const float* __restrict__ bq, const float* __restrict__ bk,
    const float* __restrict__ bv_, const float* __restrict__ bskip, const float* __restrict__ bl,
    u32* __restrict__ xrP, u32* __restrict__ qP, u32* __restrict__ kvP,
    u32* __restrict__ skipP, u32* __restrict__ xlP, u32* __restrict__ xwP,
    u32* __restrict__ ctxlinP,
    const int* __restrict__ em, const int* __restrict__ ep, const int* __restrict__ ei,
    const float* __restrict__ ea_p, const int* __restrict__ offsets,
    const int* __restrict__ ranks, int2* __restrict__ pool) {
    __shared__ ushort lds[16384];   // 32KB: one 128x128 bf16 weight
    if (blockIdx.x >= GEMM_BLKS) {
        int t = (blockIdx.x - GEMM_BLKS) * 256 + threadIdx.x;
        int seg, s; float ea = 0.f;
        if (t < EM_N) { s = em[t]; seg = em[EM_N + t]; }
        else if (t < EM_N + EP_N) { int e = t - EM_N; s = ep[e]; seg = NB + ep[EP_N + e]; ea = ea_p[e]; }
        else if (t < POOL_N) { int e = t - EM_N - EP_N; s = ei[e]; seg = 2 * NB + ei[EI_N + e]; }
        else return;
        int pos = offsets[seg] + ranks[t];   // no atomics
        pool[pos] = make_int2(s, __float_as_int(ea));
        return;
    }
    const int tid = threadIdx.x;
    const int lane = tid & 63;
    const int wv = tid >> 6;
    const int quad = lane >> 4, l16 = lane & 15;

    // ---- job decode (block-uniform): one weight x one 64-row tile ----
    int bid = blockIdx.x;
    int w, tile, M;
    const u32* A;
    if (bid < 6 * BALL_TILES) {
        int widx = bid / BALL_TILES;         // 0..5
        w = (widx < 5) ? widx : 6;           // weights 0..4 and 6 operate on ball rows
        tile = bid - widx * BALL_TILES; M = NB; A = xbB;
    } else if (bid < 6 * BALL_TILES + PLYR_TILES) {
        w = 5; tile = bid - 6 * BALL_TILES; M = NP; A = xbP;
    } else {
        w = 7; tile = bid - 6 * BALL_TILES - PLYR_TILES; M = NC; A = xbC;
    }
    u32* op; const float* bp = nullptr; const float* resid = nullptr; float scale = 1.f;
    int ostride = 64, ooff = 0;
    switch (w) {
        case 0: op = xrP; break;
        case 1: op = qP; bp = bq; scale = QSCALE; break;
        case 2: op = kvP; bp = bk; ostride = 128; ooff = 0; break;
        case 3: op = kvP; bp = bv_; ostride = 128; ooff = 64; break;
        case 4: op = skipP; bp = bskip; resid = Aball; break;
        case 5: op = xlP; break;
        case 6: op = xwP; break;
        default: op = ctxlinP; bp = bl; resid = Actx; break;
    }

    // ---- stage weight (linear copy; layout makes ds reads conflict-free) ----
    {
        const ushort* src = Wt + w * 16384;
#pragma unroll
        for (int p = 0; p < 8; p++)
            gl_lds16(src + (size_t)(p * 256 + tid) * 8, lds + p * 2048 + wv * 512);
    }

    // A fragments (issued while the stage flies)
    s8v a[4];
    {
        int r0 = tile * 64 + wv * 16 + l16; if (r0 >= M) r0 = M - 1;
        const s8v* ap = (const s8v*)(A + (size_t)r0 * 64 + quad * 4);
#pragma unroll
        for (int kt = 0; kt < 4; kt++) a[kt] = ap[kt * 4];
    }
    // bias preload (depends only on t,l16)
    float2 bias2[4];
#pragma unroll
    for (int t = 0; t < 4; t++)
        bias2[t] = bp ? ((const float2*)bp)[t * 16 + l16] : make_float2(0.f, 0.f);
    __syncthreads();   // weight staged

    const int mbase = tile * 64 + wv * 16;
#pragma unroll
    for (int t = 0; t < 4; t++) {
        f4v alo = {0.f, 0.f, 0.f, 0.f}, ahi = {0.f, 0.f, 0.f, 0.f};
#pragma unroll
        for (int kt = 0; kt < 4; kt++) {
            s8v blo = *(const s8v*)(lds + (kt * 4 + quad) * 1024 + (t * 32 + l16) * 8);
            s8v bhi = *(const s8v*)(lds + (kt * 4 + quad) * 1024 + (t * 32 + 16 + l16) * 8);
            alo = __builtin_amdgcn_mfma_f32_16x16x32_bf16(a[kt], blo, alo, 0, 0, 0);
            ahi = __builtin_amdgcn_mfma_f32_16x16x32_bf16(a[kt], bhi, ahi, 0, 0, 0);
        }
#pragma unroll
        for (int r = 0; r < 4; r++) {
            int row = mbase + quad * 4 + r;
            if (row < M) {
                float vlo = (alo[r] + bias2[t].x) * scale;
                float vhi = (ahi[r] + bias2[t].y) * scale;
                if (resid) {
                    float2 x2 = ((const float2*)resid)[(size_t)row * 64 + t * 16 + l16];
                    vlo += x2.x; vhi += x2.y;
                }
                op[(size_t)row * ostride + ooff + t * 16 + l16] = packbf(vlo, vhi);
            }
        }
    }
}

// ---------------- edge-batch helpers (ball path) ----------------
__device__ __forceinline__ void gat_batch(const u32 xv[4], const bool ok[4],
                                          float xr0, float xr1, float attx, float atty,
                                          float& n0, float& n1, float& deg) {
    float p[4], xa[4], xb[4];
#pragma unroll
    for (int i = 0; i < 4; i++) {
        xa[i] = loF(xv[i]); xb[i] = hiF(xv[i]);
        float u0 = xa[i] + xr0; u0 = u0 > 0.f ? u0 : 0.2f * u0;
        float u1 = xb[i] + xr1; u1 = u1 > 0.f ? u1 : 0.2f * u1;
        p[i] = u0 * attx + u1 * atty;
    }
#pragma unroll
    for (int m = 1; m <= 8; m <<= 1) {
#pragma unroll
        for (int i = 0; i < 4; i++) p[i] += __shfl_xor(p[i], m);
    }
#pragma unroll
    for (int i = 0; i < 4; i++) {
        p[i] = ok[i] ? exp2f(p[i]) : 0.f;
        n0 += p[i] * xa[i]; n1 += p[i] * xb[i]; deg += p[i];
    }
}

__device__ __forceinline__ void tr_batch(const u32 kk[4], const u32 vv[4],
                                         const float ea[4], const bool ok[4],
                                         float q0, float q1, float dw,
                                         float& sv0, float& sv1, float& spe, float& det) {
    float p[4];
#pragma unroll
    for (int i = 0; i < 4; i++) p[i] = q0 * loF(kk[i]) + q1 * hiF(kk[i]);
#pragma unroll
    for (int m = 1; m <= 8; m <<= 1) {
#pragma unroll
        for (int i = 0; i < 4; i++) p[i] += __shfl_xor(p[i], m);
    }
#pragma unroll
    for (int i = 0; i < 4; i++) {
        p[i] = ok[i] ? exp2f(p[i] + ea[i] * dw) : 0.f;
        sv0 += p[i] * loF(vv[i]); sv1 += p[i] * hiF(vv[i]);
        spe += p[i] * ea[i]; det += p[i];
    }
}

// ---------------- merged: ctx blocks FIRST (longest, ~37.5-edge serial gather-mean)
// then ball blocks -> long ctx chains overlap the bulk ball phase instead of forming the tail.
// LayerNorm uses fused sum/sumsq single-pass reduction (var = E[x^2]-mu^2).
__global__ __launch_bounds__(256) void ball_sage_kernel(
    const u32* __restrict__ xlP, const u32* __restrict__ xrP, const u32* __restrict__ qP,
    const u32* __restrict__ kvP, const u32* __restrict__ skipP, const u32* __restrict__ xwP,
    const u32* __restrict__ ctxlinP,
    const float* __restrict__ g_att, const float* __restrict__ g_b, const float* __restrict__ We,
    const int* __restrict__ offsets, const int* __restrict__ counts,
    const int2* __restrict__ pool,
    const float* __restrict__ ln_g, const float* __restrict__ ln_b,
    const float* __restrict__ cg, const float* __restrict__ cb,
    float* __restrict__ out) {
    __shared__ float part[4][128];
    const int wv = threadIdx.x >> 6, l = threadIdx.x & 63;

    if (blockIdx.x < NC) {
        // ---- ctx: gather-mean xw + ctxlin + LN (2-deep pipelined gather) ----
        int c = blockIdx.x;
        int beg = offsets[2 * NB + c], cnt = counts[2 * NB + c];
        float s0 = 0.f, s1 = 0.f;
        int j = wv;
        if (j < cnt) {
            int i0 = pool[beg + j].x;
            int idx1 = (j + 4 < cnt) ? beg + j + 4 : 0;
            int i1 = pool[idx1].x;
            u32 x0 = xwP[(size_t)i0 * 64 + l];
            u32 x1 = xwP[(size_t)i1 * 64 + l];
            for (; j < cnt; j += 4) {
                int idx2 = (j + 8 < cnt) ? beg + j + 8 : 0;
                int i2 = pool[idx2].x;
                s0 += loF(x0); s1 += hiF(x0);
                x0 = x1;
                x1 = xwP[(size_t)i2 * 64 + l];
            }
        }
        part[wv][l * 2] = s0; part[wv][l * 2 + 1] = s1;
        __syncthreads();
        if (wv == 0) {
            float m = fmaxf((float)cnt, 1.f);
            u32 cl = ctxlinP[(size_t)c * 64 + l];
            float v0 = (part[0][l * 2] + part[1][l * 2] + part[2][l * 2] + part[3][l * 2]) / m + loF(cl);
            float v1 = (part[0][l * 2 + 1] + part[1][l * 2 + 1] + part[2][l * 2 + 1] + part[3][l * 2 + 1]) / m + hiF(cl);
            float s = v0 + v1;
            float s2 = v0 * v0 + v1 * v1;
#pragma unroll
            for (int m2 = 1; m2 <= 32; m2 <<= 1) {
                s += __shfl_xor(s, m2);
                s2 += __shfl_xor(s2, m2);
            }
            float mu = s * (1.f / 128.f);
            float var = s2 * (1.f / 128.f) - mu * mu;
            float inv = rsqrtf(var + 1e-5f);
            float d0 = v0 - mu, d1 = v1 - mu;
            float2 g2 = ((const float2*)cg)[l];
            float2 b2 = ((const float2*)cb)[l];
            ((float2*)out)[(size_t)(NB + c) * 64 + l] =
                make_float2(d0 * inv * g2.x + b2.x, d1 * inv * g2.y + b2.y);
        }
        return;
    }

    // ---- ball path: one wave per node, pairing (2l,2l+1), head = l>>4 ----
    const int d = (blockIdx.x - NC) * 4 + wv;
    const size_t rowD = (size_t)d * 64;
    const int ds = __builtin_amdgcn_readfirstlane(d);

    // early issue: per-node rows
    u32 xr2 = xrP[rowD + l];
    u32 q2 = qP[rowD + l];
    u32 sk = skipP[rowD + l];

    // scalar segment metadata + scalar pool prefetch (both relations in parallel)
    const int begG = offsets[ds], cntG = counts[ds];
    const int begT = offsets[NB + ds], cntT = counts[NB + ds];
    int gS[8];
#pragma unroll
    for (int i = 0; i < 8; i++) { int idx = (i < cntG) ? begG + i : 0; gS[i] = pool[idx].x; }
    int tS[8]; float tE[8];
#pragma unroll
    for (int i = 0; i < 8; i++) {
        int idx = (i < cntT) ? begT + i : 0;
        int2 pr = pool[idx]; tS[i] = pr.x; tE[i] = __int_as_float(pr.y);
    }

    // issue all gathers for the <=8 fast path (both relations in flight together)
    u32 gx[8];
    if (cntG > 0) {
#pragma unroll
        for (int i = 0; i < 4; i++) gx[i] = xlP[(size_t)gS[i] * 64 + l];
        if (cntG > 4) {
#pragma unroll
            for (int i = 4; i < 8; i++) gx[i] = xlP[(size_t)gS[i] * 64 + l];
        }
    }
    u32 kk[8], vv[8];
    if (cntT > 0) {
#pragma unroll
        for (int i = 0; i < 4; i++) {
            kk[i] = kvP[(size_t)tS[i] * 128 + l];
            vv[i] = kvP[(size_t)tS[i] * 128 + 64 + l];
        }
        if (cntT > 4) {
#pragma unroll
            for (int i = 4; i < 8; i++) {
                kk[i] = kvP[(size_t)tS[i] * 128 + l];
                vv[i] = kvP[(size_t)tS[i] * 128 + 64 + l];
            }
        }
    }

    // TR edge-weight projection (q is pre-scaled by QSCALE)
    float q0 = loF(q2), q1 = hiF(q2);
    float2 we = ((const float2*)We)[l];
    float dw = q0 * we.x + q1 * we.y;
#pragma unroll
    for (int m = 1; m <= 8; m <<= 1) dw += __shfl_xor(dw, m);

    // ======== GATv2 (att pre-scaled by log2e for exp2f) ========
    float2 attv = ((const float2*)g_att)[l];
    float attx = attv.x * LOG2E, atty = attv.y * LOG2E;
    float xr0 = loF(xr2), xr1 = hiF(xr2);
    float n0 = 0.f, n1 = 0.f, deg = 0.f;
    if (cntG > 0) {
        bool ok[4];
#pragma unroll
        for (int i = 0; i < 4; i++) ok[i] = (i < cntG);
        gat_batch(&gx[0], ok, xr0, xr1, attx, atty, n0, n1, deg);
        if (cntG > 4) {
            bool ok2[4];
#pragma unroll
            for (int i = 0; i < 4; i++) ok2[i] = (4 + i < cntG);
            gat_batch(&gx[4], ok2, xr0, xr1, attx, atty, n0, n1, deg);
        }
        for (int j = 8; j < cntG; j += 4) {     // rare tail
            bool ok3[4]; u32 xv[4];
#pragma unroll
            for (int i = 0; i < 4; i++) {
                ok3[i] = (j + i < cntG);
                int idx = ok3[i] ? begG + j + i : 0;
                xv[i] = xlP[(size_t)pool[idx].x * 64 + l];
            }
            gat_batch(xv, ok3, xr0, xr1, attx, atty, n0, n1, deg);
        }
    }
    float gat0 = n0 / (deg + 1e-16f), gat1 = n1 / (deg + 1e-16f);

    // ======== TransformerConv ========
    float sv0 = 0.f, sv1 = 0.f, spe = 0.f, det = 0.f;
    if (cntT > 0) {
        bool ok[4];
#pragma unroll
        for (int i = 0; i < 4; i++) ok[i] = (i < cntT);
        tr_batch(&kk[0], &vv[0], &tE[0], ok, q0, q1, dw, sv0, sv1, spe, det);
        if (cntT > 4) {
            bool ok2[4];
#pragma unroll
            for (int i = 0; i < 4; i++) ok2[i] = (4 + i < cntT);
            tr_batch(&kk[4], &vv[4], &tE[4], ok2, q0, q1, dw, sv0, sv1, spe, det);
        }
        for (int j = 8; j < cntT; j += 4) {     // rare tail
            bool ok3[4]; u32 kt2[4], vt2[4]; float ea[4];
#pragma unroll
            for (int i = 0; i < 4; i++) {
                ok3[i] = (j + i < cntT);
                int idx = ok3[i] ? begT + j + i : 0;
                int2 pr = pool[idx];
                ea[i] = __int_as_float(pr.y);
                kt2[i] = kvP[(size_t)pr.x * 128 + l];
                vt2[i] = kvP[(size_t)pr.x * 128 + 64 + l];
            }
            tr_batch(kt2, vt2, ea, ok3, q0, q1, dw, sv0, sv1, spe, det);
        }
    }
    float tr0 = (sv0 + spe * we.x) / (det + 1e-16f);
    float tr1 = (sv1 + spe * we.y) / (det + 1e-16f);

    // ======== residual(skipP has x_ball+bskip; add g_b here) + LayerNorm (fused sum/sumsq) ========
    float2 gb2 = ((const float2*)g_b)[l];
    float val0 = loF(sk) + gb2.x + gat0 + tr0;
    float val1 = hiF(sk) + gb2.y + gat1 + tr1;
    float s = val0 + val1;
    float s2 = val0 * val0 + val1 * val1;
#pragma unroll
    for (int m = 1; m <= 32; m <<= 1) {
        s += __shfl_xor(s, m);
        s2 += __shfl_xor(s2, m);
    }
    float mu = s * (1.f / 128.f);
    float var = s2 * (1.f / 128.f) - mu * mu;
    float inv = rsqrtf(var + 1e-5f);
    float d0 = val0 - mu, d1 = val1 - mu;
    float2 g2 = ((const float2*)ln_g)[l];
    float2 b2 = ((const float2*)ln_b)[l];
    ((float2*)out)[rowD + l] = make_float2(d0 * inv * g2.x + b2.x, d1 * inv * g2.y + b2.y);
}

extern "C" void kernel_launch(void* const* d_in, const int* in_sizes, int n_in,
                              void* d_out, int out_size, void* d_ws, size_t ws_size,
                              hipStream_t stream) {
    const float* x_ball = (const float*)d_in[0];
    const float* x_player = (const float*)d_in[1];
    const float* x_context = (const float*)d_in[2];
    const int* em = (const int*)d_in[3];
    const int* ep = (const int*)d_in[4];
    const int* ei = (const int*)d_in[5];
    const float* ea_p = (const float*)d_in[6];
    const float* g_Wl = (const float*)d_in[7];
    const float* g_Wr = (const float*)d_in[8];
    const float* g_att = (const float*)d_in[9];
    const float* g_b = (const float*)d_in[10];
    const float* t_Wq = (const float*)d_in[11];
    const float* t_bq = (const float*)d_in[12];
    const float* t_Wk = (const float*)d_in[13];
    const float* t_bk = (const float*)d_in[14];
    const float* t_Wv = (const float*)d_in[15];
    const float* t_bv = (const float*)d_in[16];
    const float* t_We = (const float*)d_in[17];
    const float* t_Wskip = (const float*)d_in[18];
    const float* t_bskip = (const float*)d_in[19];
    const float* s_Wl = (const float*)d_in[20];
    const float* s_bl = (const float*)d_in[21];
    const float* s_Wr = (const float*)d_in[22];
    const float* ln_ball_g = (const float*)d_in[23];
    const float* ln_ball_b = (const float*)d_in[24];
    const float* ln_ctx_g = (const float*)d_in[25];
    const float* ln_ctx_b = (const float*)d_in[26];
    float* out = (float*)d_out;

    // ---- workspace ----
    float* ws = (float*)d_ws;
    size_t o = 0;
    int* counts = (int*)(ws + o);   o += SEG_TOT;
    int* gbase = (int*)(ws + o);    o += 1;     // zeroed with counts
    int* offsets = (int*)(ws + o);  o += SEG_TOT;
    int* ranks = (int*)(ws + o);    o += POOL_N;
    if (o & 1) o++;
    int2* pool = (int2*)(ws + o);   o += (size_t)POOL_N * 2;
    o = (o + 3) & ~(size_t)3;       // 16B-align
    ushort* Wt = (ushort*)(ws + o); o += (8 * 16384) / 2;
    u32* xbB = (u32*)(ws + o);      o += (size_t)NB * 64;
    u32* xbC = (u32*)(ws + o);      o += (size_t)NC * 64;
    u32* xbP = (u32*)(ws + o);      o += (size_t)NP * 64;
    u32* xlP = (u32*)(ws + o);      o += (size_t)NP * 64;
    u32* xrP = (u32*)(ws + o);      o += (size_t)NB * 64;
    u32* qP = (u32*)(ws + o);       o += (size_t)NB * 64;
    u32* skipP = (u32*)(ws + o);    o += (size_t)NB * 64;
    u32* xwP = (u32*)(ws + o);      o += (size_t)NB * 64;
    u32* ctxlinP = (u32*)(ws + o);  o += (size_t)NC * 64;
    if (o & 1) o++;
    u32* kvP = (u32*)(ws + o);      o += (size_t)NB * 128;

    dim3 blk(256);
    hipMemsetAsync(counts, 0, (SEG_TOT + 1) * sizeof(int), stream);
    prep_all_kernel<<<PREPALL_BLKS, blk, 0, stream>>>(
        em, ep, ei, counts, ranks, g_Wr, t_Wq, t_Wk, t_Wv, t_Wskip, g_Wl, s_Wl, s_Wr, Wt,
        x_ball, x_context, x_player, xbB, xbC, xbP, out);
    scan_kernel<<<NPART, blk, 0, stream>>>(counts, offsets, gbase);
    gemm6_fill_kernel<<<GEMM_BLKS + FILL_BLKS, blk, 0, stream>>>(
        xbB, xbP, xbC, x_ball, x_context, Wt, t_bq, t_bk, t_bv, t_bskip, s_bl,
        xrP, qP, kvP, skipP, xlP, xwP, ctxlinP, em, ep, ei, ea_p, offsets, ranks, pool);
    ball_sage_kernel<<<BBALL + NC, blk, 0, stream>>>(
        xlP, xrP, qP, kvP, skipP, xwP, ctxlinP, g_att, g_b, t_We,
        offsets, counts, pool, ln_ball_g, ln_ball_b, ln_ctx_g, ln_ctx_b, out);
}